// Round 1
// baseline (309.739 us; speedup 1.0000x reference)
//
#include <hip/hip_runtime.h>
#include <hip/hip_bf16.h>
#include <math.h>

// Problem constants (fixed by setup_inputs)
#define N_NODES   50000
#define N_EDGES   800000
#define N_REL     1000
#define DIM       128
#define DEPTH_L   2
#define OUT_STRIDE (DIM * (DEPTH_L + 1))   // 384

// ---------------------------------------------------------------------------
// Kernel 1: per-relation precompute.
//   rel_hat[r]  = rel_emb[r] / max(||rel_emb[r]||, 1e-12)       [R, D]
//   att_rel[l][r] = rel_hat[r] . attn_k[l]                      [DEPTH, R]
// One wave (64 lanes) per relation; each lane holds elems d and d+64.
// ---------------------------------------------------------------------------
__global__ __launch_bounds__(64) void prep_rel_kernel(
    const float* __restrict__ rel_emb,
    const float* __restrict__ attn_k,
    float* __restrict__ rel_hat,
    float* __restrict__ att_rel)
{
    int r = blockIdx.x;
    int lane = threadIdx.x;
    float v0 = rel_emb[r * DIM + lane];
    float v1 = rel_emb[r * DIM + lane + 64];
    float ss = v0 * v0 + v1 * v1;
    #pragma unroll
    for (int o = 32; o >= 1; o >>= 1) ss += __shfl_xor(ss, o);
    float inv = 1.0f / fmaxf(sqrtf(ss), 1e-12f);
    float t0 = v0 * inv, t1 = v1 * inv;
    rel_hat[r * DIM + lane]      = t0;
    rel_hat[r * DIM + lane + 64] = t1;
    #pragma unroll
    for (int l = 0; l < DEPTH_L; ++l) {
        float d = t0 * attn_k[l * DIM + lane] + t1 * attn_k[l * DIM + lane + 64];
        #pragma unroll
        for (int o = 32; o >= 1; o >>= 1) d += __shfl_xor(d, o);
        if (lane == 0) att_rel[l * N_REL + r] = d;
    }
}

// ---------------------------------------------------------------------------
// Kernel 2: CSR row pointers from the sorted src array (binary search).
// ---------------------------------------------------------------------------
__global__ __launch_bounds__(256) void rowptr_kernel(
    const int* __restrict__ src, int* __restrict__ rp)
{
    int n = blockIdx.x * blockDim.x + threadIdx.x;
    if (n > N_NODES) return;
    int lo = 0, hi = N_EDGES;
    while (lo < hi) {
        int mid = (lo + hi) >> 1;
        if (src[mid] < n) lo = mid + 1; else hi = mid;
    }
    rp[n] = lo;
}

// ---------------------------------------------------------------------------
// Kernel 3: out[:, 0:128] = tanh(features)  (vectorized float4)
// ---------------------------------------------------------------------------
__global__ __launch_bounds__(256) void tanh0_kernel(
    const float* __restrict__ feat, float* __restrict__ out)
{
    int i = blockIdx.x * blockDim.x + threadIdx.x;      // over N*D/4 float4s
    if (i >= N_NODES * DIM / 4) return;
    float4 v = reinterpret_cast<const float4*>(feat)[i];
    int n = (i * 4) / DIM;
    int d = (i * 4) % DIM;
    float4 o;
    o.x = tanhf(v.x); o.y = tanhf(v.y); o.z = tanhf(v.z); o.w = tanhf(v.w);
    *reinterpret_cast<float4*>(&out[(size_t)n * OUT_STRIDE + d]) = o;
}

// ---------------------------------------------------------------------------
// Kernel 4: one attention layer. One wave per node (4 waves / 256-thr block).
//   Phase 1: per-node online softmax stats (m, s) over edge logits.
//   Phase 2: serial edge loop; wave-parallel over D=128 (2 floats/lane):
//     h' = h - 2 (h.t) t ;  acc += softmax_w * h'
//   Write tanh(acc) to the layer's output column block.
// feat_in / feat_out point at column offsets inside d_out (row stride 384).
// ---------------------------------------------------------------------------
__global__ __launch_bounds__(256) void layer_kernel(
    const float* __restrict__ feat_in,
    float* __restrict__ feat_out,
    const int* __restrict__ dst,
    const int* __restrict__ relid,
    const float* __restrict__ rval,
    const int* __restrict__ rp,
    const float* __restrict__ rel_hat,
    const float* __restrict__ att_rel_l)
{
    int wid  = threadIdx.x >> 6;
    int lane = threadIdx.x & 63;
    int node = blockIdx.x * 4 + wid;
    if (node >= N_NODES) return;

    int start = rp[node], end = rp[node + 1];
    float acc0 = 0.f, acc1 = 0.f;

    if (start < end) {
        // ---- Phase 1: softmax stats (lane-parallel over edges) ----
        float m = -INFINITY, s = 0.f;
        for (int e = start + lane; e < end; e += 64) {
            float rv = rval[e];
            float logit = (rv == 0.f) ? 0.f : att_rel_l[relid[e]];
            if (logit > m) { s = s * __expf(m - logit) + 1.f; m = logit; }
            else           { s += __expf(logit - m); }
        }
        #pragma unroll
        for (int o = 32; o >= 1; o >>= 1) {
            float m2 = __shfl_xor(m, o);
            float s2 = __shfl_xor(s, o);
            float mn = fmaxf(m, m2);
            float sn = (mn == -INFINITY) ? 0.f
                     : s * __expf(m - mn) + s2 * __expf(m2 - mn);
            m = mn; s = sn;
        }
        float inv_s = 1.0f / s;

        // ---- Phase 2: weighted reflected accumulate ----
        for (int e = start; e < end; ++e) {
            int   dv = dst[e];
            int   rl = relid[e];
            float rv = rval[e];
            const float* hrow = feat_in + (size_t)dv * OUT_STRIDE;
            float h0 = hrow[lane];
            float h1 = hrow[lane + 64];
            float t0, t1, logit;
            if (rv == 0.f) { t0 = 0.f; t1 = 0.f; logit = 0.f; }
            else {
                t0 = rel_hat[rl * DIM + lane];
                t1 = rel_hat[rl * DIM + lane + 64];
                logit = att_rel_l[rl];
            }
            float dot = h0 * t0 + h1 * t1;
            #pragma unroll
            for (int o = 32; o >= 1; o >>= 1) dot += __shfl_xor(dot, o);
            float w = __expf(logit - m) * inv_s;
            acc0 += w * (h0 - 2.f * dot * t0);
            acc1 += w * (h1 - 2.f * dot * t1);
        }
    }
    feat_out[(size_t)node * OUT_STRIDE + lane]      = tanhf(acc0);
    feat_out[(size_t)node * OUT_STRIDE + lane + 64] = tanhf(acc1);
}

// ---------------------------------------------------------------------------
extern "C" void kernel_launch(void* const* d_in, const int* in_sizes, int n_in,
                              void* d_out, int out_size, void* d_ws, size_t ws_size,
                              hipStream_t stream)
{
    const float* features = (const float*)d_in[0];
    const float* rel_emb  = (const float*)d_in[1];
    const int*   adj      = (const int*)d_in[2];   // [2, E]: src | dst
    const int*   r_index  = (const int*)d_in[3];   // [2, E]: arange | rel
    const float* r_val    = (const float*)d_in[4];
    const float* attn_k   = (const float*)d_in[8]; // [DEPTH, D]
    float* out = (float*)d_out;

    const int* src   = adj;
    const int* dst   = adj + N_EDGES;
    const int* relid = r_index + N_EDGES;

    // Workspace carve-up (~712 KB)
    float* rel_hat = (float*)d_ws;                       // R*D
    float* att_rel = rel_hat + (size_t)N_REL * DIM;      // DEPTH*R
    int*   rp      = (int*)(att_rel + DEPTH_L * N_REL);  // N+1

    prep_rel_kernel<<<N_REL, 64, 0, stream>>>(rel_emb, attn_k, rel_hat, att_rel);
    rowptr_kernel<<<(N_NODES + 1 + 255) / 256, 256, 0, stream>>>(src, rp);
    tanh0_kernel<<<(N_NODES * DIM / 4 + 255) / 256, 256, 0, stream>>>(features, out);

    for (int l = 0; l < DEPTH_L; ++l) {
        layer_kernel<<<(N_NODES + 3) / 4, 256, 0, stream>>>(
            out + l * DIM,          // previous layer's feature block
            out + (l + 1) * DIM,    // this layer's feature block
            dst, relid, r_val, rp, rel_hat, att_rel + l * N_REL);
    }
}